// Round 9
// baseline (383.327 us; speedup 1.0000x reference)
//
#include <hip/hip_runtime.h>

// ConvLSTM2D via MFMA implicit-GEMM. B=8,T=16,H=W=64,Cin=32,F=64,3x3 SAME.
// Round 16: kill the B-ring; B streams global->VGPR (1-deep dbuf) and the
// block grows to 1024 thr / 16 waves = 4 waves/SIMD from ONE block.
// Why: R8 (B-in-regs @ 2 waves/SIMD) failed for lack of TLP, not because
// rings are better; the 96KB ring is what FORCED 1 block/CU + 2 waves/SIMD.
// The 256-block grid (full-machine constraint) blocks 2-blocks/CU, so the
// only occupancy path is more waves per block. Waves = 2 pxgrp x 8 ngrp,
// wave tile 64px x 32ch (acc 32 VGPR, total ~100 < 128 cap for 16 waves).
// LDS = xs 14.4 + hs 25.9 = 40.3 KB. K-loop BARRIER-FREE (B wave-private
// in regs, A-LDS read-only); one barrier publishes hs between s=8 and s=9.
// wpk per (s,nt) = contiguous 1KB line -> coalesced; per-XCD wpk slice
// 432KB L2-resident; same-iter pxgrp-pair reuse hits L1.
// Cost: gates span waves -> zbuf epilogue exchange (R12-proven), 32KB
// aliasing dead xs/hs, 4 chunks of 32px.
// Keeps R14/R15: async h-issue, cpre prefetch (s=17), XCD b=bid&7 map.
// Pipe model/CU-iter: MFMA 621 | A-LDS ~571 | B-L2 ~585 -> ~700 cyc with
// 4-wave TLP vs current ~1300.

#define TSTEPS 16

typedef short bf16x8 __attribute__((ext_vector_type(8)));
typedef float f32x4 __attribute__((ext_vector_type(4)));

__device__ __forceinline__ float hsig(float x) {
    return fminf(fmaxf((x + 3.0f) * (1.0f / 6.0f), 0.0f), 1.0f);
}

__device__ __forceinline__ unsigned short f2bf(float f) {
    union { float f; unsigned int u; } v; v.f = f;
    unsigned int r = v.u + 0x7fffu + ((v.u >> 16) & 1u);  // RNE
    return (unsigned short)(r >> 16);
}

// ---- weight prepack: Wg(3,3,32,256), Ug(3,3,64,256) fp32 -> bf16 B-frags ----
// layout out[s(27)][nt(16)][lane(64)][8]: per (s,nt) one contiguous 1 KB line.
__global__ __launch_bounds__(256)
void prepack_w(const float* __restrict__ Wg, const float* __restrict__ Ug,
               unsigned short* __restrict__ out)
{
    int idx = blockIdx.x * 256 + threadIdx.x;   // 27*16*64 = 27648
    if (idx >= 27648) return;
    int lane = idx & 63;
    int nt   = (idx >> 6) & 15;
    int s    = idx >> 10;
    int col = lane & 15, quad = lane >> 4;
    int n = nt * 16 + col;
    int k0 = quad * 8;
    const float* src;
    if (s < 9) {
        src = Wg + ((size_t)s * 32 + k0) * 256 + n;
    } else {
        int ss = s - 9; int tap = ss >> 1; int half = ss & 1;
        src = Ug + ((size_t)tap * 64 + half * 32 + k0) * 256 + n;
    }
    unsigned short tmp[8];
    #pragma unroll
    for (int j = 0; j < 8; ++j) tmp[j] = f2bf(src[(size_t)j * 256]);
    *(uint4*)(out + (size_t)idx * 8) = *(uint4*)tmp;
}

// ---- one ConvLSTM step (NS = 9 for t==0, 27 otherwise) ----
template<int NS>
__global__ __launch_bounds__(1024)
__attribute__((amdgpu_waves_per_eu(4, 4)))
void convlstm_step(const float* __restrict__ x,       // (B,T,64,64,32) fp32
                   const unsigned short* __restrict__ wpk,
                   const float* __restrict__ bias,    // (256)
                   const unsigned short* __restrict__ h_in, // bf16 (B,64,64,64)
                   float* __restrict__ c_st,          // fp32 (B,64,64,64) = d_out
                   unsigned short* __restrict__ h_out,// bf16 ping
                   int t, int is_last)
{
    constexpr bool HP = (NS == 27);

    // LDS: xs [0,14400), hs [14400,40320); epilogue zbuf f32[2048][4] = 32 KB
    // aliases [0,32768) (xs/hs dead by then).
    __shared__ __align__(16) unsigned char smem[40320];
    unsigned short* xs_s = (unsigned short*)smem;
    unsigned short* hs_s = (unsigned short*)(smem + 14400);
    float*          zbuf = (float*)smem;

    const int tid  = threadIdx.x;
    // XCD-aware decode: batch = bid&7 -> one batch's 32 tiles on one XCD.
    const int bid  = blockIdx.x;
    const int b    = bid & 7;
    const int tile = bid >> 3;             // 0..31
    const int gx0  = (tile & 7) * 8;
    const int gy0  = (tile >> 3) * 16;

    const int lane  = tid & 63;
    const int w     = tid >> 6;        // wave 0..15
    const int pxgrp = w >> 3;          // 0: rows 0-7, 1: rows 8-15
    const int ngrp  = w & 7;           // n-tiles {2*ngrp, 2*ngrp+1}
    const int quad  = lane >> 4;
    const int m     = lane & 15;

    // ---- h halo: ISSUE loads into regs early (hide under x-stage).
    // 1440 items / 1024 thr = 2 rounds (2nd partial: tid < 416).
    uint4 hv0 = make_uint4(0u,0u,0u,0u), hv1 = make_uint4(0u,0u,0u,0u);
    int ho0 = 0, ho1 = -1;
    if constexpr (HP) {
        const unsigned short* hb = h_in + ((size_t)b * (64 * 64 * 64));
        auto issueH = [&](int idx, uint4& v, int& off) {
            int pix = idx >> 3, q = idx & 7;
            int iy = pix / 10, ix = pix - iy * 10;
            int gy = gy0 + iy - 1, gx = gx0 + ix - 1;
            if ((unsigned)gy < 64u && (unsigned)gx < 64u)
                v = *(const uint4*)(hb + ((size_t)(gy * 64 + gx) * 64) + q * 8);
            off = pix * 72 + q * 8;
        };
        issueH(tid, hv0, ho0);
        if (tid < 416) issueH(tid + 1024, hv1, ho1);
    }

    // ---- stage x halo (fp32 -> bf16); h loads in flight meanwhile ----
    {
        const float* xt = x + (((size_t)b * TSTEPS + t) * (size_t)(64 * 64 * 32));
        #pragma unroll 2
        for (int idx = tid; idx < 180 * 8; idx += 1024) {
            int pix = idx >> 3, q = idx & 7;
            int iy = pix / 10, ix = pix - iy * 10;
            int gy = gy0 + iy - 1, gx = gx0 + ix - 1;
            unsigned short o[4] = {0, 0, 0, 0};
            if ((unsigned)gy < 64u && (unsigned)gx < 64u) {
                float4 v = *(const float4*)(xt + ((size_t)(gy * 64 + gx) * 32) + q * 4);
                o[0] = f2bf(v.x); o[1] = f2bf(v.y); o[2] = f2bf(v.z); o[3] = f2bf(v.w);
            }
            *(ushort4*)(xs_s + pix * 40 + q * 4) = *(ushort4*)o;
        }
    }
    __syncthreads();   // xs_s visible (h still in regs)

    // per-thread A maps: p = mt*16 + m within the wave's 64px
    int xb[4], hb_[4];
    #pragma unroll
    for (int mt = 0; mt < 4; ++mt) {
        int p = mt * 16 + m;
        int row = pxgrp * 8 + (p >> 3);
        int cc  = p & 7;
        xb[mt]  = (row * 10 + cc) * 40 + quad * 8;
        hb_[mt] = (row * 10 + cc) * 72 + quad * 8;
    }

    // acc init = bias; wave's n = (2*ngrp+g)*16 + m
    f32x4 acc[4][2];   // [mt][g]
    #pragma unroll
    for (int g = 0; g < 2; ++g) {
        float bv = bias[(2 * ngrp + g) * 16 + m];
        f32x4 bi = (f32x4){bv, bv, bv, bv};
        #pragma unroll
        for (int mt = 0; mt < 4; ++mt) acc[mt][g] = bi;
    }

    // cpre: c_prev for this thread's 8 epilogue cells (cell = tid + j*1024
    // of chunk q). Prefetched at s==17 (HP) so latency hides under K-loop.
    float cpre[4][2];
    if constexpr (!HP) {
        #pragma unroll
        for (int q = 0; q < 4; ++q) { cpre[q][0] = 0.0f; cpre[q][1] = 0.0f; }
    }

    // ---- B: demand global->VGPR, 1-deep double buffer ----
    auto loadB = [&](int s, bf16x8* dst) {
        #pragma unroll
        for (int g = 0; g < 2; ++g)
            dst[g] = *(const bf16x8*)(wpk + ((size_t)(s * 16 + 2 * ngrp + g) * 64 + lane) * 8);
    };

    bf16x8 bC[2], bN[2];
    loadB(0, bC);

    // ---- K-loop: barrier-free (B wave-private, A read-only) ----
    #pragma unroll
    for (int s = 0; s < NS; ++s) {
        if (s + 1 < NS) loadB(s + 1, bN);

        bf16x8 a[4];
        if (s < 9) {
            int taplin = (s / 3) * 10 + (s % 3);
            #pragma unroll
            for (int mt = 0; mt < 4; ++mt)
                a[mt] = *(const bf16x8*)(xs_s + xb[mt] + taplin * 40);
        } else {
            int ss = s - 9, tap = ss >> 1, half = ss & 1;
            int taplin = (tap / 3) * 10 + (tap % 3);
            #pragma unroll
            for (int mt = 0; mt < 4; ++mt)
                a[mt] = *(const bf16x8*)(hs_s + hb_[mt] + taplin * 72 + half * 32);
        }

        #pragma unroll
        for (int g = 0; g < 2; ++g)
            #pragma unroll
            for (int mt = 0; mt < 4; ++mt)
                acc[mt][g] = __builtin_amdgcn_mfma_f32_16x16x32_bf16(a[mt], bC[g], acc[mt][g], 0, 0, 0);

        #pragma unroll
        for (int i = 0; i < 2; ++i) bC[i] = bN[i];

        // publish hs between the x-phase (s<9) and h-phase (s>=9)
        if constexpr (HP) {
            if (s == 8) {
                *(uint4*)(hs_s + ho0) = hv0;
                if (ho1 >= 0) *(uint4*)(hs_s + ho1) = hv1;
                __syncthreads();
            }
            if (s == 17) {
                // prefetch c_prev for the epilogue cells (8 scattered loads)
                #pragma unroll
                for (int q = 0; q < 4; ++q)
                    #pragma unroll
                    for (int j = 0; j < 2; ++j) {
                        int cell = tid + j * 1024;          // 0..2047
                        int pl = cell >> 6, fch = cell & 63;
                        int row = q * 4 + (pl >> 3), col = pl & 7;
                        size_t gidx = (((size_t)b * 64 + (gy0 + row)) * 64 + (gx0 + col)) * 64 + fch;
                        cpre[q][j] = c_st[gidx];
                    }
            }
        }
    }

    // ---- epilogue: cross-wave gate exchange (zbuf aliases xs/hs) ----
    // chunk q = 4 rows (32 px): rows [4q, 4q+4). Written by pxgrp q>>1
    // waves from acc mt in {2*(q&1), 2*(q&1)+1}.
    __syncthreads();   // all K-loop LDS reads done; zbuf may overwrite
    #pragma unroll
    for (int q = 0; q < 4; ++q) {
        if (q) __syncthreads();            // prev chunk's reads done
        if (pxgrp == (q >> 1)) {
            #pragma unroll
            for (int mtl = 0; mtl < 2; ++mtl) {
                int mt = 2 * (q & 1) + mtl;
                #pragma unroll
                for (int g = 0; g < 2; ++g)
                    #pragma unroll
                    for (int r = 0; r < 4; ++r) {
                        int p = mt * 16 + quad * 4 + r;      // 0..63 in-wave
                        int rowl = (p >> 3) - (q & 1) * 4;   // 0..3
                        int pl = rowl * 8 + (p & 7);         // 0..31
                        int n = (2 * ngrp + g) * 16 + m;     // 0..255
                        zbuf[((pl * 64) + (n & 63)) * 4 + (n >> 6)] = acc[mt][g][r];
                    }
            }
        }
        __syncthreads();
        // read 4 gates per cell; cells = tid, tid+1024 (coalesced fch)
        #pragma unroll
        for (int j = 0; j < 2; ++j) {
            int cell = tid + j * 1024;
            int pl = cell >> 6, fch = cell & 63;
            int row = q * 4 + (pl >> 3), col = pl & 7;
            float4 z = *(const float4*)(zbuf + (size_t)cell * 4);
            size_t gidx = (((size_t)b * 64 + (gy0 + row)) * 64 + (gx0 + col)) * 64 + fch;
            float cn = hsig(z.y) * cpre[q][j] + hsig(z.x) * fmaxf(z.z, 0.0f);
            float hn = hsig(z.w) * fmaxf(cn, 0.0f);
            if (is_last) {
                c_st[gidx] = hn;            // d_out gets final h (fp32)
            } else {
                c_st[gidx] = cn;
                h_out[gidx] = f2bf(hn);
            }
        }
    }
}

extern "C" void kernel_launch(void* const* d_in, const int* in_sizes, int n_in,
                              void* d_out, int out_size, void* d_ws, size_t ws_size,
                              hipStream_t stream) {
    const float* x  = (const float*)d_in[0];
    const float* Wg = (const float*)d_in[1];
    const float* Ug = (const float*)d_in[2];
    const float* bs = (const float*)d_in[3];

    // ws layout: [packed weights 442368 B][h0 bf16 4 MB][h1 bf16 4 MB]
    unsigned short* wpk = (unsigned short*)d_ws;
    unsigned short* h0  = (unsigned short*)((char*)d_ws + 27 * 16 * 64 * 8 * 2);
    unsigned short* h1  = h0 + (size_t)8 * 64 * 64 * 64;
    float* cS = (float*)d_out;

    prepack_w<<<108, 256, 0, stream>>>(Wg, Ug, wpk);

    dim3 grid(256);    // 1D; decode: b = bid&7 (XCD), tile = bid>>3
    dim3 block(1024);  // 16 waves = 4 waves/SIMD from one block
    for (int t = 0; t < TSTEPS; ++t) {
        const unsigned short* hin = (t == 0) ? h0 : ((t & 1) ? h0 : h1);
        unsigned short* hout = (t & 1) ? h1 : h0;
        if (t == 0) {
            convlstm_step<9><<<grid, block, 0, stream>>>(x, wpk, bs, hin, cS, hout, t, 0);
        } else {
            convlstm_step<27><<<grid, block, 0, stream>>>(x, wpk, bs, hin, cS, hout,
                                                          t, (t == TSTEPS - 1) ? 1 : 0);
        }
    }
}